// Round 3
// baseline (2459.199 us; speedup 1.0000x reference)
//
#include <hip/hip_runtime.h>
#include <hip/hip_bf16.h>

#define HID 64
#define BN 192            // nodes per bucket
#define AST 68            // accum LDS stride in floats (pad 64 -> 68, breaks bank aliasing)
#define MAXB 1024         // max buckets supported

typedef short  bf16x8 __attribute__((ext_vector_type(8)));
typedef float  f32x4  __attribute__((ext_vector_type(4)));

__device__ inline float bf2f(unsigned int u16) {
    union { unsigned int i; float f; } v; v.i = u16 << 16; return v.f;
}
__device__ inline unsigned short f2bf(float f) {
    union { float f; unsigned int i; } v; v.f = f;
    unsigned int u = v.i;
    u += 0x7FFFu + ((u >> 16) & 1u);      // round-to-nearest-even
    return (unsigned short)(u >> 16);
}

// ---------------- bucket build ----------------------------------------------
// phase A: per-block LDS histogram of dst buckets, merged to global
__global__ __launch_bounds__(1024) void bucket_hist(
        const int* __restrict__ dst, int* __restrict__ cnt, int E, int nb) {
    __shared__ int h[MAXB];
    for (int i = threadIdx.x; i < nb; i += 1024) h[i] = 0;
    __syncthreads();
    int base = blockIdx.x * 16384;
    for (int i = 0; i < 16; ++i) {
        int e = base + i * 1024 + threadIdx.x;
        if (e < E) atomicAdd(&h[dst[e] / BN], 1);
    }
    __syncthreads();
    for (int i = threadIdx.x; i < nb; i += 1024)
        if (h[i]) atomicAdd(&cnt[i], h[i]);
}

// exclusive scan of cnt[nb] -> base[nb+1]; cursor (padded 16 ints) = base
__global__ void bucket_scan(const int* __restrict__ cnt, int* __restrict__ base,
                            int* __restrict__ cursor, int nb, int total) {
    int lane = threadIdx.x;   // 64 threads
    int running = 0;
    int nch = (nb + 63) / 64;
    for (int c = 0; c < nch; ++c) {
        int i = c * 64 + lane;
        int v = (i < nb) ? cnt[i] : 0;
        int s = v;
        for (int d = 1; d < 64; d <<= 1) {
            int t = __shfl_up(s, d);
            if (lane >= d) s += t;
        }
        if (i < nb) {
            int ex = running + s - v;
            base[i] = ex;
            cursor[i * 16] = ex;
        }
        running += __shfl(s, 63);
    }
    if (lane == 0) base[nb] = total;
}

// phase B: per-block hist -> one global reservation per (block,bucket) ->
// place packed records (src<<8 | dstLocal). Order within bucket is arbitrary.
__global__ __launch_bounds__(1024) void bucket_scatter(
        const int* __restrict__ src, const int* __restrict__ dst,
        int* __restrict__ cursor, unsigned int* __restrict__ rec, int E, int nb) {
    __shared__ int h[MAXB];
    __shared__ int gb[MAXB];
    __shared__ int lc[MAXB];
    for (int i = threadIdx.x; i < nb; i += 1024) { h[i] = 0; lc[i] = 0; }
    __syncthreads();
    int base = blockIdx.x * 16384;
    for (int i = 0; i < 16; ++i) {
        int e = base + i * 1024 + threadIdx.x;
        if (e < E) atomicAdd(&h[dst[e] / BN], 1);
    }
    __syncthreads();
    for (int i = threadIdx.x; i < nb; i += 1024) {
        int c = h[i];
        if (c) gb[i] = atomicAdd(&cursor[i * 16], c);
    }
    __syncthreads();
    for (int i = 0; i < 16; ++i) {
        int e = base + i * 1024 + threadIdx.x;
        if (e < E) {
            int d = dst[e];
            int b = d / BN;
            int lp = atomicAdd(&lc[b], 1);
            rec[gb[b] + lp] = ((unsigned int)src[e] << 8) | (unsigned int)(d - b * BN);
        }
    }
}

// ---------------- dtype prep ------------------------------------------------
__global__ void cvt_bf16(const float* __restrict__ x, unsigned int* __restrict__ xb, int n4) {
    int i = blockIdx.x * 256 + threadIdx.x;
    if (i >= n4) return;
    float4 v = reinterpret_cast<const float4*>(x)[i];
    xb[i * 2]     = ((unsigned int)f2bf(v.y) << 16) | f2bf(v.x);
    xb[i * 2 + 1] = ((unsigned int)f2bf(v.w) << 16) | f2bf(v.z);
}

// Wt[l][c][k] bf16: k<64 -> Wrel[l][k][c], k>=64 -> Wroot[l][k-64][c]
__global__ void prep_w(const float* __restrict__ Wrel, const float* __restrict__ Wroot,
                       unsigned short* __restrict__ Wt, int nl) {
    int i = blockIdx.x * 256 + threadIdx.x;
    if (i >= nl * 64 * 128) return;
    int k = i & 127, c = (i >> 7) & 63, l = i >> 13;
    float v = (k < 64) ? Wrel[(size_t)l * 4096 + k * 64 + c]
                       : Wroot[(size_t)l * 4096 + (k - 64) * 64 + c];
    Wt[i] = f2bf(v);
}

// ---------------- fused layer: gather(LDS scatter-add) + GEMM + pool --------
// block = one bucket (192 nodes), 256 threads.
__global__ __launch_bounds__(256, 2) void fused_layer(
        const unsigned int* __restrict__ rec, const int* __restrict__ bbase,
        const unsigned int* __restrict__ xb,       // [N][32] uints (bf16 pairs)
        const int* __restrict__ batch,
        const unsigned short* __restrict__ Wt,     // [64][128] bf16
        const float* __restrict__ brel,
        unsigned short* __restrict__ yout,         // [N][64] bf16
        float* __restrict__ x_add,                 // [G][64] f32
        int N, int nb) {
    __shared__ float accum[BN * AST];
    __shared__ float pool[16 * 64];
    int b = blockIdx.x;
    int n0 = b * BN;
    int nNodes = min(BN, N - n0);
    int tid = threadIdx.x;
    for (int i = tid; i < BN * AST; i += 256) accum[i] = 0.f;
    for (int i = tid; i < 16 * 64; i += 256) pool[i] = 0.f;
    __syncthreads();

    // ---- edge phase: half-wave (32 lanes = 64 ch) per record, 4 contiguous/iter
    int e0 = bbase[b], e1 = bbase[b + 1];
    int hw = tid >> 5, ch = tid & 31;
    for (int e = e0 + hw * 4; e < e1; e += 32) {
#pragma unroll
        for (int j = 0; j < 4; ++j) {
            int ee = e + j;
            if (ee < e1) {
                unsigned int r = rec[ee];
                int s = r >> 8;
                int dl = r & 255;
                unsigned int p = xb[(size_t)s * 32 + ch];
                atomicAdd(&accum[dl * AST + ch * 2],     bf2f(p & 0xFFFFu));
                atomicAdd(&accum[dl * AST + ch * 2 + 1], bf2f(p >> 16));
            }
        }
    }
    __syncthreads();

    // ---- GEMM + epilogue: wave per 16-node tile (3 tiles/wave)
    int lane = tid & 63, wv = tid >> 6;
    int r = lane & 15, kb = lane >> 4;
    int gmin = batch[n0];
    int gspan = batch[n0 + nNodes - 1] - gmin + 1;
    int nT = nNodes >> 4;                       // nNodes % 16 == 0 for N=100000
    const unsigned short* xs = reinterpret_cast<const unsigned short*>(xb);
    for (int t = wv; t < nT; t += 4) {
        int nodeBase = n0 + t * 16;
        f32x4 acc[4] = {};
#pragma unroll
        for (int ks = 0; ks < 4; ++ks) {
            bf16x8 a;
            if (ks < 2) {
                const float* ap = &accum[(t * 16 + r) * AST + ks * 32 + kb * 8];
#pragma unroll
                for (int j = 0; j < 8; ++j) a[j] = (short)f2bf(ap[j]);
            } else {
                a = *reinterpret_cast<const bf16x8*>(
                        xs + (size_t)(nodeBase + r) * 64 + (ks - 2) * 32 + kb * 8);
            }
            const unsigned short* wrow = Wt + (size_t)r * 128 + kb * 8 + ks * 32;
#pragma unroll
            for (int ct = 0; ct < 4; ++ct) {
                bf16x8 bb = *reinterpret_cast<const bf16x8*>(wrow + (size_t)ct * 16 * 128);
                acc[ct] = __builtin_amdgcn_mfma_f32_16x16x32_bf16(a, bb, acc[ct], 0, 0, 0);
            }
        }
#pragma unroll
        for (int reg = 0; reg < 4; ++reg) {
            int node = nodeBase + kb * 4 + reg;
            int g = batch[node] - gmin;
#pragma unroll
            for (int ct = 0; ct < 4; ++ct) {
                int c = ct * 16 + r;
                float v = acc[ct][reg] + brel[c];
                v = fmaxf(v, 0.f);
                yout[(size_t)node * 64 + c] = f2bf(v);
                if (gspan <= 16) atomicAdd(&pool[g * 64 + c], v);
                else             atomicAdd(&x_add[(size_t)(gmin + g) * 64 + c], v);
            }
        }
    }
    __syncthreads();
    if (gspan <= 16) {
        for (int i = tid; i < gspan * 64; i += 256)
            atomicAdd(&x_add[(size_t)gmin * 64 + i], pool[i]);
    }
}

// ---------------- final MLP --------------------------------------------------
__global__ __launch_bounds__(64) void mlp_kernel(
        const float* __restrict__ x_add,
        const float* __restrict__ W1, const float* __restrict__ b1,
        const float* __restrict__ W2, const float* __restrict__ b2,
        const float* __restrict__ W3, const float* __restrict__ b3,
        float* __restrict__ out, int ngraph) {
    int g = blockIdx.x;
    if (g >= ngraph) return;
    int lane = threadIdx.x;
    __shared__ float h1s[64];
    __shared__ float h2s[32];
    const float* xa = x_add + (size_t)g * HID;
    float s = b1[lane];
#pragma unroll
    for (int k = 0; k < 64; ++k) s += xa[k] * W1[k * 64 + lane];
    h1s[lane] = fmaxf(s, 0.f);
    __syncthreads();
    if (lane < 32) {
        float s2 = b2[lane];
#pragma unroll
        for (int k = 0; k < 64; ++k) s2 += h1s[k] * W2[k * 32 + lane];
        h2s[lane] = fmaxf(s2, 0.f);
    }
    __syncthreads();
    if (lane == 0) {
        float o = b3[0];
        for (int k = 0; k < 32; ++k) o += h2s[k] * W3[k];
        out[g] = o;
    }
}

// ---------------- launcher --------------------------------------------------
extern "C" void kernel_launch(void* const* d_in, const int* in_sizes, int n_in,
                              void* d_out, int out_size, void* d_ws, size_t ws_size,
                              hipStream_t stream) {
    const float* x0    = (const float*)d_in[0];
    const int*   ei    = (const int*)d_in[1];
    const int*   batch = (const int*)d_in[2];
    const float* Wrel  = (const float*)d_in[3];
    const float* brel  = (const float*)d_in[4];
    const float* Wroot = (const float*)d_in[5];
    const float* W1    = (const float*)d_in[6];
    const float* b1    = (const float*)d_in[7];
    const float* W2    = (const float*)d_in[8];
    const float* b2    = (const float*)d_in[9];
    const float* W3    = (const float*)d_in[10];
    const float* b3    = (const float*)d_in[11];
    float* out = (float*)d_out;

    const int N = in_sizes[0] / HID;          // 100000
    const int E = in_sizes[1] / 2;            // 1600000
    const int G = out_size;                   // 1000
    const int L = in_sizes[3] / (HID * HID);  // 3
    const int NB = (N + BN - 1) / BN;         // 521

    const int* src = ei;
    const int* dst = ei + E;

    char* w = (char*)d_ws;
    size_t off = 0;
    auto alloc = [&](size_t bytes) {
        void* p = w + off;
        off += (bytes + 255) & ~(size_t)255;
        return p;
    };
    unsigned short* xb0   = (unsigned short*)alloc((size_t)N * HID * 2);
    unsigned short* xbA   = (unsigned short*)alloc((size_t)N * HID * 2);
    unsigned short* xbB   = (unsigned short*)alloc((size_t)N * HID * 2);
    unsigned short* Wt    = (unsigned short*)alloc((size_t)L * 64 * 128 * 2);
    unsigned int*   recs  = (unsigned int*)alloc((size_t)E * 4);
    float* x_add  = (float*)alloc((size_t)G * HID * 4);
    int*   bcnt   = (int*)alloc((size_t)NB * 4);
    int*   bbase  = (int*)alloc((size_t)(NB + 1) * 4);
    int*   bcur   = (int*)alloc((size_t)NB * 16 * 4);   // 64B-padded cursors
    (void)ws_size;

    const int TB = 256;

    hipMemsetAsync(bcnt, 0, (size_t)NB * 4, stream);
    hipMemsetAsync(x_add, 0, (size_t)G * HID * 4, stream);

    int sortBlocks = (E + 16383) / 16384;
    bucket_hist<<<sortBlocks, 1024, 0, stream>>>(dst, bcnt, E, NB);
    bucket_scan<<<1, 64, 0, stream>>>(bcnt, bbase, bcur, NB, E);
    bucket_scatter<<<sortBlocks, 1024, 0, stream>>>(src, dst, bcur, recs, E, NB);

    cvt_bf16<<<(N * 16 + TB - 1) / TB, TB, 0, stream>>>(x0, (unsigned int*)xb0, N * 16);
    prep_w<<<(L * 64 * 128 + TB - 1) / TB, TB, 0, stream>>>(Wrel, Wroot, Wt, L);

    for (int i = 0; i < L; ++i) {
        const unsigned short* xin = (i == 0) ? xb0 : ((i == 1) ? xbA : xbB);
        unsigned short* xout = (i == 1) ? xbB : xbA;   // L0->xbA, L1->xbB, L2->xbA
        fused_layer<<<NB, TB, 0, stream>>>(recs, bbase,
                (const unsigned int*)xin, batch,
                Wt + (size_t)i * 64 * 128, brel + (size_t)i * HID,
                xout, x_add, N, NB);
    }

    mlp_kernel<<<G, 64, 0, stream>>>(x_add, W1, b1, W2, b2, W3, b3, out, G);
}

// Round 4
// 264.677 us; speedup vs baseline: 9.2913x; 9.2913x over previous
//
#include <hip/hip_runtime.h>
#include <hip/hip_bf16.h>

#define HID 64
#define BN 192            // nodes per bucket (dl fits in 8 bits)
#define MAXB 1024         // max buckets supported

typedef short  bf16x8 __attribute__((ext_vector_type(8)));
typedef float  f32x4  __attribute__((ext_vector_type(4)));

__device__ inline float bf2f(unsigned int u16) {
    union { unsigned int i; float f; } v; v.i = u16 << 16; return v.f;
}
__device__ inline unsigned short f2bf(float f) {
    union { float f; unsigned int i; } v; v.f = f;
    unsigned int u = v.i;
    u += 0x7FFFu + ((u >> 16) & 1u);      // round-to-nearest-even
    return (unsigned short)(u >> 16);
}

// ---------------- bucket build ----------------------------------------------
__global__ __launch_bounds__(1024) void bucket_hist(
        const int* __restrict__ dst, int* __restrict__ cnt, int E, int nb) {
    __shared__ int h[MAXB];
    for (int i = threadIdx.x; i < nb; i += 1024) h[i] = 0;
    __syncthreads();
    int base = blockIdx.x * 16384;
    for (int i = 0; i < 16; ++i) {
        int e = base + i * 1024 + threadIdx.x;
        if (e < E) atomicAdd(&h[dst[e] / BN], 1);
    }
    __syncthreads();
    for (int i = threadIdx.x; i < nb; i += 1024)
        if (h[i]) atomicAdd(&cnt[i], h[i]);
}

__global__ void bucket_scan(const int* __restrict__ cnt, int* __restrict__ base,
                            int* __restrict__ cursor, int nb, int total) {
    int lane = threadIdx.x;   // 64 threads
    int running = 0;
    int nch = (nb + 63) / 64;
    for (int c = 0; c < nch; ++c) {
        int i = c * 64 + lane;
        int v = (i < nb) ? cnt[i] : 0;
        int s = v;
        for (int d = 1; d < 64; d <<= 1) {
            int t = __shfl_up(s, d);
            if (lane >= d) s += t;
        }
        if (i < nb) {
            int ex = running + s - v;
            base[i] = ex;
            cursor[i * 16] = ex;
        }
        running += __shfl(s, 63);
    }
    if (lane == 0) base[nb] = total;
}

__global__ __launch_bounds__(1024) void bucket_scatter(
        const int* __restrict__ src, const int* __restrict__ dst,
        int* __restrict__ cursor, unsigned int* __restrict__ rec, int E, int nb) {
    __shared__ int h[MAXB];
    __shared__ int gb[MAXB];
    __shared__ int lc[MAXB];
    for (int i = threadIdx.x; i < nb; i += 1024) { h[i] = 0; lc[i] = 0; }
    __syncthreads();
    int base = blockIdx.x * 16384;
    for (int i = 0; i < 16; ++i) {
        int e = base + i * 1024 + threadIdx.x;
        if (e < E) atomicAdd(&h[dst[e] / BN], 1);
    }
    __syncthreads();
    for (int i = threadIdx.x; i < nb; i += 1024) {
        int c = h[i];
        if (c) gb[i] = atomicAdd(&cursor[i * 16], c);
    }
    __syncthreads();
    for (int i = 0; i < 16; ++i) {
        int e = base + i * 1024 + threadIdx.x;
        if (e < E) {
            int d = dst[e];
            int b = d / BN;
            int lp = atomicAdd(&lc[b], 1);
            rec[gb[b] + lp] = ((unsigned int)src[e] << 8) | (unsigned int)(d - b * BN);
        }
    }
}

// per-bucket: count local nodes, scan in LDS, write node-ordered col + rowp.
__global__ __launch_bounds__(256) void bucket_to_csr(
        const unsigned int* __restrict__ rec, const int* __restrict__ bbase,
        int* __restrict__ col, int* __restrict__ rowp, int N, int nb) {
    __shared__ int tmp[256];
    __shared__ int cur[256];
    int b = blockIdx.x;
    int n0 = b * BN;
    int nNodes = min(BN, N - n0);
    int tid = threadIdx.x;
    int e0 = bbase[b], e1 = bbase[b + 1];
    tmp[tid] = 0;
    __syncthreads();
    for (int e = e0 + tid; e < e1; e += 256)
        atomicAdd(&tmp[rec[e] & 255u], 1);
    __syncthreads();
    int my = tmp[tid];
    // Hillis-Steele inclusive scan over 256
    for (int offd = 1; offd < 256; offd <<= 1) {
        int t = (tid >= offd) ? tmp[tid - offd] : 0;
        __syncthreads();
        tmp[tid] += t;
        __syncthreads();
    }
    int ex = tmp[tid] - my;           // exclusive
    cur[tid] = ex;
    if (tid < nNodes) rowp[n0 + tid] = e0 + ex;
    if (b == nb - 1 && tid == 0) rowp[N] = e1;
    __syncthreads();
    for (int e = e0 + tid; e < e1; e += 256) {
        unsigned int r = rec[e];
        int p = atomicAdd(&cur[r & 255u], 1);
        col[e0 + p] = (int)(r >> 8);
    }
}

__global__ void batch_starts(const int* __restrict__ batch, int* __restrict__ bstart,
                             int n, int ngraph) {
    int i = blockIdx.x * blockDim.x + threadIdx.x;
    if (i >= n) return;
    int b = batch[i];
    int prev = (i == 0) ? -1 : batch[i - 1];
    for (int g = prev + 1; g <= b; ++g) bstart[g] = i;
    if (i == n - 1) {
        for (int g = b + 1; g <= ngraph; ++g) bstart[g] = n;
    }
}

// ---------------- dtype prep ------------------------------------------------
__global__ void cvt_bf16(const float* __restrict__ x, unsigned int* __restrict__ xb, int n4) {
    int i = blockIdx.x * 256 + threadIdx.x;
    if (i >= n4) return;
    float4 v = reinterpret_cast<const float4*>(x)[i];
    xb[i * 2]     = ((unsigned int)f2bf(v.y) << 16) | f2bf(v.x);
    xb[i * 2 + 1] = ((unsigned int)f2bf(v.w) << 16) | f2bf(v.z);
}

// Wt[l][c][k] bf16: k<64 -> Wrel[l][k][c], k>=64 -> Wroot[l][k-64][c]
__global__ void prep_w(const float* __restrict__ Wrel, const float* __restrict__ Wroot,
                       unsigned short* __restrict__ Wt, int nl) {
    int i = blockIdx.x * 256 + threadIdx.x;
    if (i >= nl * 64 * 128) return;
    int k = i & 127, c = (i >> 7) & 63, l = i >> 13;
    float v = (k < 64) ? Wrel[(size_t)l * 4096 + k * 64 + c]
                       : Wroot[(size_t)l * 4096 + (k - 64) * 64 + c];
    Wt[i] = f2bf(v);
}

// ---------------- gather: wave per node, 8-wide batched loads per half ------
__global__ __launch_bounds__(256) void gather_bf16(
        const int* __restrict__ rowp, const int* __restrict__ col,
        const unsigned int* __restrict__ xb,      // [N][32] uints (2 bf16 each)
        unsigned int* __restrict__ aggb, int n) {
    int wid = (blockIdx.x * 256 + threadIdx.x) >> 6;
    int lane = threadIdx.x & 63;
    if (wid >= n) return;
    int h = lane >> 5, ch = lane & 31;
    int e0 = rowp[wid], e1 = rowp[wid + 1];
    float ax = 0.f, ay = 0.f;
    // half h handles 8-edge chunks at eb = e0 + h*8, e0 + 16 + h*8, ...
    for (int eb = e0 + h * 8; eb < e1; eb += 16) {
        int c[8];
#pragma unroll
        for (int j = 0; j < 8; ++j) c[j] = col[min(eb + j, e1 - 1)];
        unsigned int p[8];
#pragma unroll
        for (int j = 0; j < 8; ++j) p[j] = xb[(size_t)c[j] * 32 + ch];
#pragma unroll
        for (int j = 0; j < 8; ++j) {
            unsigned int q = (eb + j < e1) ? p[j] : 0u;
            ax += bf2f(q & 0xFFFFu);
            ay += bf2f(q >> 16);
        }
    }
    ax += __shfl(ax, lane ^ 32);
    ay += __shfl(ay, lane ^ 32);
    if (h == 0)
        aggb[(size_t)wid * 32 + ch] = ((unsigned int)f2bf(ay) << 16) | f2bf(ax);
}

// ---------------- GEMM: wave = 16 nodes x 64 cols, K=128 --------------------
// C/D: col = lane&15, row = 4*(lane>>4)+reg  (m89-verified).
__global__ __launch_bounds__(256) void gemm_mfma(
        const unsigned short* __restrict__ aggb, const unsigned short* __restrict__ xinb,
        unsigned short* __restrict__ yout,
        const unsigned short* __restrict__ Wt,   // [64][128]
        const float* __restrict__ brel, int n) {
    int wave = (blockIdx.x * 256 + threadIdx.x) >> 6;
    int lane = threadIdx.x & 63;
    int n0 = wave * 16;
    if (n0 >= n) return;
    int r = lane & 15, kb = lane >> 4;
    f32x4 acc[4] = {};
    const unsigned short* arow = aggb + (size_t)(n0 + r) * 64 + kb * 8;
    const unsigned short* xrow = xinb + (size_t)(n0 + r) * 64 + kb * 8;
    const unsigned short* wrow = Wt + (size_t)r * 128 + kb * 8;
#pragma unroll
    for (int ks = 0; ks < 4; ++ks) {
        const unsigned short* ap = (ks < 2) ? (arow + (ks & 1) * 32)
                                            : (xrow + (ks & 1) * 32);
        bf16x8 a = *reinterpret_cast<const bf16x8*>(ap);
#pragma unroll
        for (int ct = 0; ct < 4; ++ct) {
            bf16x8 b = *reinterpret_cast<const bf16x8*>(wrow + (size_t)ct * 16 * 128 + ks * 32);
            acc[ct] = __builtin_amdgcn_mfma_f32_16x16x32_bf16(a, b, acc[ct], 0, 0, 0);
        }
    }
#pragma unroll
    for (int ct = 0; ct < 4; ++ct) {
        int c = ct * 16 + r;
        float bias = brel[c];
#pragma unroll
        for (int reg = 0; reg < 4; ++reg) {
            int node = n0 + kb * 4 + reg;
            float v = acc[ct][reg] + bias;
            yout[(size_t)node * 64 + c] = f2bf(fmaxf(v, 0.f));
        }
    }
}

// ---------------- pool: block per graph --------------------------------------
__global__ __launch_bounds__(256) void pool_bf16(
        const unsigned int* __restrict__ y,      // [N][32]
        const int* __restrict__ bstart, float* __restrict__ x_add, int ngraph) {
    int g = blockIdx.x;
    if (g >= ngraph) return;
    int lane = threadIdx.x & 63, w = threadIdx.x >> 6;
    int h = lane >> 5, ch = lane & 31;
    __shared__ float2 part[4][32];
    int s0 = bstart[g], s1 = bstart[g + 1];
    float ax = 0.f, ay = 0.f;
    for (int nd = s0 + w * 2 + h; nd < s1; nd += 8) {
        unsigned int p = y[(size_t)nd * 32 + ch];
        ax += bf2f(p & 0xFFFFu);
        ay += bf2f(p >> 16);
    }
    ax += __shfl(ax, lane ^ 32);
    ay += __shfl(ay, lane ^ 32);
    if (h == 0) part[w][ch] = make_float2(ax, ay);
    __syncthreads();
    if (threadIdx.x < 32) {
        float2 s = part[0][threadIdx.x];
        s.x += part[1][threadIdx.x].x + part[2][threadIdx.x].x + part[3][threadIdx.x].x;
        s.y += part[1][threadIdx.x].y + part[2][threadIdx.x].y + part[3][threadIdx.x].y;
        float2* xa = reinterpret_cast<float2*>(x_add + (size_t)g * 64);
        float2 cur = xa[threadIdx.x];
        xa[threadIdx.x] = make_float2(cur.x + s.x, cur.y + s.y);
    }
}

// ---------------- final MLP --------------------------------------------------
__global__ __launch_bounds__(64) void mlp_kernel(
        const float* __restrict__ x_add,
        const float* __restrict__ W1, const float* __restrict__ b1,
        const float* __restrict__ W2, const float* __restrict__ b2,
        const float* __restrict__ W3, const float* __restrict__ b3,
        float* __restrict__ out, int ngraph) {
    int g = blockIdx.x;
    if (g >= ngraph) return;
    int lane = threadIdx.x;
    __shared__ float h1s[64];
    __shared__ float h2s[32];
    const float* xa = x_add + (size_t)g * HID;
    float s = b1[lane];
#pragma unroll
    for (int k = 0; k < 64; ++k) s += xa[k] * W1[k * 64 + lane];
    h1s[lane] = fmaxf(s, 0.f);
    __syncthreads();
    if (lane < 32) {
        float s2 = b2[lane];
#pragma unroll
        for (int k = 0; k < 64; ++k) s2 += h1s[k] * W2[k * 32 + lane];
        h2s[lane] = fmaxf(s2, 0.f);
    }
    __syncthreads();
    if (lane == 0) {
        float o = b3[0];
        for (int k = 0; k < 32; ++k) o += h2s[k] * W3[k];
        out[g] = o;
    }
}

// ---------------- launcher --------------------------------------------------
extern "C" void kernel_launch(void* const* d_in, const int* in_sizes, int n_in,
                              void* d_out, int out_size, void* d_ws, size_t ws_size,
                              hipStream_t stream) {
    const float* x0    = (const float*)d_in[0];
    const int*   ei    = (const int*)d_in[1];
    const int*   batch = (const int*)d_in[2];
    const float* Wrel  = (const float*)d_in[3];
    const float* brel  = (const float*)d_in[4];
    const float* Wroot = (const float*)d_in[5];
    const float* W1    = (const float*)d_in[6];
    const float* b1    = (const float*)d_in[7];
    const float* W2    = (const float*)d_in[8];
    const float* b2    = (const float*)d_in[9];
    const float* W3    = (const float*)d_in[10];
    const float* b3    = (const float*)d_in[11];
    float* out = (float*)d_out;

    const int N = in_sizes[0] / HID;          // 100000
    const int E = in_sizes[1] / 2;            // 1600000
    const int G = out_size;                   // 1000
    const int L = in_sizes[3] / (HID * HID);  // 3
    const int NB = (N + BN - 1) / BN;         // 521

    const int* src = ei;
    const int* dst = ei + E;

    char* w = (char*)d_ws;
    size_t off = 0;
    auto alloc = [&](size_t bytes) {
        void* p = w + off;
        off += (bytes + 255) & ~(size_t)255;
        return p;
    };
    unsigned short* xb0   = (unsigned short*)alloc((size_t)N * HID * 2);
    unsigned short* xbA   = (unsigned short*)alloc((size_t)N * HID * 2);
    unsigned short* xbB   = (unsigned short*)alloc((size_t)N * HID * 2);
    unsigned short* aggb  = (unsigned short*)alloc((size_t)N * HID * 2);
    unsigned short* Wt    = (unsigned short*)alloc((size_t)L * 64 * 128 * 2);
    unsigned int*   recs  = (unsigned int*)alloc((size_t)E * 4);
    int*   col    = (int*)alloc((size_t)E * 4);
    int*   rowp   = (int*)alloc((size_t)(N + 1) * 4);
    float* x_add  = (float*)alloc((size_t)G * HID * 4);
    int*   bcnt   = (int*)alloc((size_t)NB * 4);
    int*   bbase  = (int*)alloc((size_t)(NB + 1) * 4);
    int*   bcur   = (int*)alloc((size_t)NB * 16 * 4);   // 64B-padded cursors
    int*   bstart = (int*)alloc((size_t)(G + 1) * 4);
    (void)ws_size;

    const int TB = 256;

    hipMemsetAsync(bcnt, 0, (size_t)NB * 4, stream);
    hipMemsetAsync(x_add, 0, (size_t)G * HID * 4, stream);

    int sortBlocks = (E + 16383) / 16384;
    bucket_hist<<<sortBlocks, 1024, 0, stream>>>(dst, bcnt, E, NB);
    bucket_scan<<<1, 64, 0, stream>>>(bcnt, bbase, bcur, NB, E);
    bucket_scatter<<<sortBlocks, 1024, 0, stream>>>(src, dst, bcur, recs, E, NB);
    bucket_to_csr<<<NB, TB, 0, stream>>>(recs, bbase, col, rowp, N, NB);
    batch_starts<<<(N + TB - 1) / TB, TB, 0, stream>>>(batch, bstart, N, G);

    cvt_bf16<<<(N * 16 + TB - 1) / TB, TB, 0, stream>>>(x0, (unsigned int*)xb0, N * 16);
    prep_w<<<(L * 64 * 128 + TB - 1) / TB, TB, 0, stream>>>(Wrel, Wroot, Wt, L);

    int gatherBlocks = (N * 64 + TB - 1) / TB;        // wave per node
    int gemmBlocks   = ((N + 15) / 16 * 64 + TB - 1) / TB;
    for (int i = 0; i < L; ++i) {
        const unsigned short* xin = (i == 0) ? xb0 : ((i == 1) ? xbA : xbB);
        unsigned short* xout = (i == 1) ? xbB : xbA;  // L0->xbA, L1->xbB, L2->xbA
        gather_bf16<<<gatherBlocks, TB, 0, stream>>>(rowp, col,
                (const unsigned int*)xin, (unsigned int*)aggb, N);
        gemm_mfma<<<gemmBlocks, TB, 0, stream>>>(aggb, xin, xout,
                Wt + (size_t)i * 64 * 128, brel + (size_t)i * HID, N);
        pool_bf16<<<G, TB, 0, stream>>>((const unsigned int*)xout, bstart, x_add, G);
    }

    mlp_kernel<<<G, 64, 0, stream>>>(x_add, W1, b1, W2, b2, W3, b3, out, G);
}